// Round 4
// 808.233 us; speedup vs baseline: 1.0052x; 1.0052x over previous
//
#include <hip/hip_runtime.h>
#include <hip/hip_bf16.h>
#include <cstdint>
#include <cstddef>

typedef _Float16 half8 __attribute__((ext_vector_type(8)));
typedef _Float16 half4 __attribute__((ext_vector_type(4)));
typedef float floatx4 __attribute__((ext_vector_type(4)));
typedef unsigned long long u64;

#define B_ 256
#define T_ 168
#define H_ 1024
#define WS_ 64
#define LAG_ 168
#define LAT_ 128

__device__ __forceinline__ float fast_sigmoid(float x) {
    return __builtin_amdgcn_rcpf(1.f + __expf(-x));
}
__device__ __forceinline__ float fast_tanh(float x) {
    return 1.f - 2.f * __builtin_amdgcn_rcpf(__expf(2.f * x) + 1.f);
}

// ---------------- fp32 -> fp16 conversion (merged: 3 buffers, 1 launch) ----
__global__ void cvt_all(const float4* __restrict__ a, half4* __restrict__ da, int na,
                        const float4* __restrict__ b, half4* __restrict__ db, int nb,
                        const float4* __restrict__ c, half4* __restrict__ dc, int nc) {
    int i = blockIdx.x * blockDim.x + threadIdx.x;
    const float4* s;
    half4* d;
    int j = i;
    if (j < na) { s = a; d = da; }
    else {
        j -= na;
        if (j < nb) { s = b; d = db; }
        else {
            j -= nb;
            if (j >= nc) return;
            s = c; d = dc;
        }
    }
    float4 v = s[j];
    half4 o;
    o[0] = (_Float16)v.x; o[1] = (_Float16)v.y;
    o[2] = (_Float16)v.z; o[3] = (_Float16)v.w;
    d[j] = o;
}

// ---------------- encoder layers 1,2 ----------------
__global__ void enc12(const float* __restrict__ in, const float* __restrict__ W,
                      const float* __restrict__ bias, float* __restrict__ outb, int infeat) {
    int r = blockIdx.x, j = threadIdx.x;
    const float* row = in + (size_t)r * infeat;
    const float* w   = W  + (size_t)j * infeat;
    float s = bias[j];
    for (int k = 0; k < infeat; ++k) s += row[k] * w[k];
    outb[(size_t)r * blockDim.x + j] = (s >= 0.f) ? s : 0.01f * s;
}

// ---------------- encoder layer 3 ----------------
__global__ void enc3(const float* __restrict__ h2, const float* __restrict__ W3,
                     const float* __restrict__ b3, float* __restrict__ hprev32,
                     _Float16* __restrict__ h0f16) {
    __shared__ float s[LAT_];
    int r = blockIdx.x;
    if (threadIdx.x < LAT_) s[threadIdx.x] = h2[(size_t)r * LAT_ + threadIdx.x];
    __syncthreads();
    for (int j = threadIdx.x; j < H_; j += 256) {
        const float* w = W3 + (size_t)j * LAT_;
        float acc = b3[j];
        #pragma unroll 8
        for (int k = 0; k < LAT_; ++k) acc += s[k] * w[k];
        hprev32[(size_t)r * H_ + j] = acc;
        h0f16[(size_t)r * H_ + j]   = (_Float16)acc;
    }
}

// ---------------- persistent GRU: phase-pipelined exchange ----------------
// R13: back to R9's proven agent-scope mechanics (R10/R12's sc0-asm fast path
// failed twice with identical signatures; the only unverifiable ingredients
// were the global_*-sc0 mnemonics / s_getreg / 2x template body — all dropped).
// Congestion attack instead:
//  (1) PER-BLOCK flags (was per-wave): producers drain per-wave, one extra
//      __syncthreads, tid0 stores a single flag. Consumers poll 16 lines with
//      lanes 0..15 only (was 64 lines x 64 lanes) -> 16x fewer poll loads in
//      flight at MALL, 4x fewer flag lines. Phase blocking set is UNCHANGED
//      (phase g needs producer blocks qi=4g..4g+3 entirely, all waves).
//  (2) pv shuffle-reduce moved between h-publish store and its vmcnt(0) drain
//      (hides part of the publish RTT under DS-pipe work).
// R9 fix retained: __threadfence_block() between Hsh f16 writes / u64 read.
__global__ __launch_bounds__(256, 1) void gru_persistent(
    _Float16* __restrict__ hbuf,
    const float* __restrict__ hprev32, const _Float16* __restrict__ whh16,
    const _Float16* __restrict__ wih16, const _Float16* __restrict__ x16,
    const float* __restrict__ bih, const float* __restrict__ bhh,
    const float* __restrict__ Wo, float* __restrict__ partials,
    unsigned* __restrict__ bar)
{
    __shared__ __align__(16) _Float16 Ash[16 * 1032];
    __shared__ __align__(16) _Float16 Wsh[192 * 72];
    __shared__ __align__(16) _Float16 Hsh[4 * 256];   // per-wave 16x16 transpose segments

    const int tid  = threadIdx.x;
    const int w    = tid >> 6;
    const int lane = tid & 63;
    const int m16  = lane & 15;
    const int quad = lane >> 4;
    const int pi   = blockIdx.x & 15;
    const int qi   = blockIdx.x >> 4;
    const int pi16 = pi << 4;
    const int u    = (qi << 6) + (w << 4) + m16;

    // Wih slice -> LDS (once)
    for (int idx = tid; idx < 1536; idx += 256) {
        int rowl = idx >> 3, ch = idx & 7;
        int g = rowl >> 6, ru = rowl & 63;
        *(uint4*)(&Wsh[rowl * 72 + (ch << 3)]) =
            *(const uint4*)(wih16 + (size_t)(((g << 10) + (qi << 6) + ru) << 6) + (ch << 3));
    }

    // Resident Whh: r,z gates (AGPR-backed)
    half8 br[32], bz[32];
    {
        const _Float16* p0 = whh16 + ((size_t)u << 10) + (quad << 3);
        const _Float16* p1 = whh16 + ((size_t)(H_ + u) << 10) + (quad << 3);
        #pragma unroll
        for (int c = 0; c < 32; ++c) br[c] = *(const half8*)(p0 + (c << 5));
        #pragma unroll
        for (int c = 0; c < 32; ++c) bz[c] = *(const half8*)(p1 + (c << 5));
    }
    const _Float16* bnp = whh16 + ((size_t)(2 * H_ + u) << 10) + (quad << 3);

    const float b_r  = bih[u]          + bhh[u];
    const float b_z  = bih[H_ + u]     + bhh[H_ + u];
    const float b_in = bih[2 * H_ + u];
    const float b_hn = bhh[2 * H_ + u];
    const float wo_u = Wo[u];

    float hreg[4];
    #pragma unroll
    for (int i = 0; i < 4; ++i)
        hreg[i] = hprev32[((size_t)(pi16 + (quad << 2) + i) << 10) + u];

    __syncthreads();

    // per-BLOCK flag lines (64B apart): flag for producer block (pi, qi)
    unsigned* flag_self       = bar + (((pi << 4) | qi) << 4);
    const unsigned* flag_peer = bar + (((pi << 4) | (lane & 15)) << 4); // lanes 0..15 use
    const int srow = tid >> 4;     // staging: this thread's local row
    const int sch  = tid & 15;     // 32B chunk (16 units)
    const int prow = lane >> 2;    // publish: row, 8B chunk
    const int pc4  = lane & 3;

    for (int t = 0; t < T_; ++t) {
        const _Float16* hsrc = hbuf + (size_t)(t & 3) * (B_ * H_);
        _Float16*       hdst = hbuf + (size_t)((t + 1) & 3) * (B_ * H_);

        // h-independent prefetch (flies under the poll)
        half8 ax0 = *(const half8*)(x16 + (((size_t)t << 8) + pi16 + m16) * WS_ + (quad << 3));
        half8 ax1 = *(const half8*)(x16 + (((size_t)t << 8) + pi16 + m16) * WS_ + 32 + (quad << 3));
        half8 bnA[8], bnB[8];
        #pragma unroll
        for (int j = 0; j < 8; ++j) bnA[j] = *(const half8*)(bnp + (j << 5));

        const unsigned need = (unsigned)t;
        u64 rdy = 0;

        // wait phase 0: producer blocks qi=0..3 of this pi-group (bits 0..3)
        while ((rdy & 0xFull) != 0xFull) {
            unsigned f = 0;
            if (lane < 16)
                f = __hip_atomic_load(flag_peer, __ATOMIC_RELAXED, __HIP_MEMORY_SCOPE_AGENT);
            rdy |= __ballot(f >= need);
            if ((rdy & 0xFull) != 0xFull) __builtin_amdgcn_s_sleep(1);
        }
        // issue phase-0 A loads
        u64 va0, va1, va2, va3;
        {
            const _Float16* s = hsrc + ((size_t)(pi16 + srow) << 10) + (sch << 4);
            va0 = __hip_atomic_load((const u64*)(s + 0),  __ATOMIC_RELAXED, __HIP_MEMORY_SCOPE_AGENT);
            va1 = __hip_atomic_load((const u64*)(s + 4),  __ATOMIC_RELAXED, __HIP_MEMORY_SCOPE_AGENT);
            va2 = __hip_atomic_load((const u64*)(s + 8),  __ATOMIC_RELAXED, __HIP_MEMORY_SCOPE_AGENT);
            va3 = __hip_atomic_load((const u64*)(s + 12), __ATOMIC_RELAXED, __HIP_MEMORY_SCOPE_AGENT);
        }

        floatx4 acc_r  = {b_r,  b_r,  b_r,  b_r };
        floatx4 acc_z  = {b_z,  b_z,  b_z,  b_z };
        floatx4 acc_in = {b_in, b_in, b_in, b_in};
        floatx4 acc_hn = {b_hn, b_hn, b_hn, b_hn};

        // gi = x_t @ Wih^T (fills the phase-0 stage window)
        {
            half8 p0 = *(const half8*)(&Wsh[((w << 4) + m16) * 72        + (quad << 3)]);
            half8 p1 = *(const half8*)(&Wsh[(64 + (w << 4) + m16) * 72   + (quad << 3)]);
            half8 p2 = *(const half8*)(&Wsh[(128 + (w << 4) + m16) * 72  + (quad << 3)]);
            acc_r  = __builtin_amdgcn_mfma_f32_16x16x32_f16(ax0, p0, acc_r,  0, 0, 0);
            acc_z  = __builtin_amdgcn_mfma_f32_16x16x32_f16(ax0, p1, acc_z,  0, 0, 0);
            acc_in = __builtin_amdgcn_mfma_f32_16x16x32_f16(ax0, p2, acc_in, 0, 0, 0);
            half8 q0 = *(const half8*)(&Wsh[((w << 4) + m16) * 72        + 32 + (quad << 3)]);
            half8 q1 = *(const half8*)(&Wsh[(64 + (w << 4) + m16) * 72   + 32 + (quad << 3)]);
            half8 q2 = *(const half8*)(&Wsh[(128 + (w << 4) + m16) * 72  + 32 + (quad << 3)]);
            acc_r  = __builtin_amdgcn_mfma_f32_16x16x32_f16(ax1, q0, acc_r,  0, 0, 0);
            acc_z  = __builtin_amdgcn_mfma_f32_16x16x32_f16(ax1, q1, acc_z,  0, 0, 0);
            acc_in = __builtin_amdgcn_mfma_f32_16x16x32_f16(ax1, q2, acc_in, 0, 0, 0);
        }

        // 4 phases: write staged A -> barrier -> poll+issue next phase -> MFMA this phase
        #pragma unroll
        for (int g = 0; g < 4; ++g) {
            {
                _Float16* d = &Ash[srow * 1032 + (g << 8) + (sch << 4)];
                *(u64*)(d + 0)  = va0;
                *(u64*)(d + 4)  = va1;
                *(u64*)(d + 8)  = va2;
                *(u64*)(d + 12) = va3;
            }
            __syncthreads();
            if (g < 3) {
                const u64 mask = 0xFull << ((g + 1) << 2);
                while ((rdy & mask) != mask) {
                    unsigned f = 0;
                    if (lane < 16)
                        f = __hip_atomic_load(flag_peer, __ATOMIC_RELAXED, __HIP_MEMORY_SCOPE_AGENT);
                    rdy |= __ballot(f >= need);
                    if ((rdy & mask) != mask) __builtin_amdgcn_s_sleep(1);
                }
                const _Float16* s = hsrc + ((size_t)(pi16 + srow) << 10) + ((g + 1) << 8) + (sch << 4);
                va0 = __hip_atomic_load((const u64*)(s + 0),  __ATOMIC_RELAXED, __HIP_MEMORY_SCOPE_AGENT);
                va1 = __hip_atomic_load((const u64*)(s + 4),  __ATOMIC_RELAXED, __HIP_MEMORY_SCOPE_AGENT);
                va2 = __hip_atomic_load((const u64*)(s + 8),  __ATOMIC_RELAXED, __HIP_MEMORY_SCOPE_AGENT);
                va3 = __hip_atomic_load((const u64*)(s + 12), __ATOMIC_RELAXED, __HIP_MEMORY_SCOPE_AGENT);
                #pragma unroll
                for (int j = 0; j < 8; ++j)
                    bnB[j] = *(const half8*)(bnp + ((((g + 1) << 3) + j) << 5));
            }
            #pragma unroll
            for (int j = 0; j < 8; ++j) {
                const int c = (g << 3) + j;
                half8 a = *(const half8*)(&Ash[m16 * 1032 + (c << 5) + (quad << 3)]);
                acc_r  = __builtin_amdgcn_mfma_f32_16x16x32_f16(a, br[c], acc_r,  0, 0, 0);
                acc_z  = __builtin_amdgcn_mfma_f32_16x16x32_f16(a, bz[c], acc_z,  0, 0, 0);
                acc_hn = __builtin_amdgcn_mfma_f32_16x16x32_f16(a, bnA[j], acc_hn, 0, 0, 0);
            }
            if (g < 3) {
                #pragma unroll
                for (int j = 0; j < 8; ++j) bnA[j] = bnB[j];
            }
        }

        // epilogue
        float pv[4];
        #pragma unroll
        for (int i = 0; i < 4; ++i) {
            float rg = fast_sigmoid(acc_r[i]);
            float zg = fast_sigmoid(acc_z[i]);
            float ng = fast_tanh(acc_in[i] + rg * acc_hn[i]);
            float hn2 = (1.f - zg) * ng + zg * hreg[i];
            hreg[i] = hn2;
            pv[i] = hn2 * wo_u;
            Hsh[(w << 8) + ((quad << 2) + i) * 16 + m16] = (_Float16)hn2;
        }
        // R9 FIX: order the f16 Hsh writes before the u64 read (compiler + DS pipe)
        __threadfence_block();
        {
            u64 hv = *(const u64*)(&Hsh[(w << 8) + prow * 16 + (pc4 << 2)]);
            __hip_atomic_store(
                (u64*)(hdst + ((size_t)(pi16 + prow) << 10) + (qi << 6) + (w << 4) + (pc4 << 2)),
                hv, __ATOMIC_RELAXED, __HIP_MEMORY_SCOPE_AGENT);
        }
        // shuffle-reduce pv while the publish store is in flight (hides RTT)
        #pragma unroll
        for (int m = 1; m < 16; m <<= 1) {
            #pragma unroll
            for (int i = 0; i < 4; ++i) pv[i] += __shfl_xor(pv[i], m);
        }
        asm volatile("s_waitcnt vmcnt(0)" ::: "memory");  // this wave's publish drained
        __syncthreads();                                   // all 4 waves drained
        if (tid == 0)
            __hip_atomic_store(flag_self, (unsigned)(t + 1),
                               __ATOMIC_RELAXED, __HIP_MEMORY_SCOPE_AGENT);
        if (m16 == 0) {
            #pragma unroll
            for (int i = 0; i < 4; ++i)
                partials[((size_t)t * B_ + pi16 + (quad << 2) + i) * 64 + (qi << 2) + w] = pv[i];
        }
    }
}

// ---------------- final reduce ----------------
__global__ void out_reduce(const float* __restrict__ partials, const float* __restrict__ bo,
                           float* __restrict__ out) {
    int t = blockIdx.x, r = threadIdx.x;
    const float* p = partials + ((size_t)t * B_ + r) * 64;
    float s = 0.f;
    #pragma unroll
    for (int i = 0; i < 64; ++i) s += p[i];
    out[(size_t)r * T_ + t] = s + bo[0];
}

extern "C" void kernel_launch(void* const* d_in, const int* in_sizes, int n_in,
                              void* d_out, int out_size, void* d_ws, size_t ws_size,
                              hipStream_t stream) {
    const float* lag  = (const float*)d_in[0];
    const float* curr = (const float*)d_in[1];
    const float* W1   = (const float*)d_in[2];
    const float* b1   = (const float*)d_in[3];
    const float* W2   = (const float*)d_in[4];
    const float* b2   = (const float*)d_in[5];
    const float* W3   = (const float*)d_in[6];
    const float* b3   = (const float*)d_in[7];
    const float* Wih  = (const float*)d_in[8];
    const float* Whh  = (const float*)d_in[9];
    const float* bih  = (const float*)d_in[10];
    const float* bhh  = (const float*)d_in[11];
    const float* Wo   = (const float*)d_in[12];
    const float* bo   = (const float*)d_in[13];
    float* out = (float*)d_out;

    char* ws = (char*)d_ws;
    size_t off = 0;
    auto alloc = [&](size_t bytes) -> void* {
        void* p = ws + off;
        off += (bytes + 255) & ~(size_t)255;
        return p;
    };
    _Float16* whh16 = (_Float16*)alloc((size_t)3 * H_ * H_ * 2);
    _Float16* wih16 = (_Float16*)alloc((size_t)3 * H_ * WS_ * 2);
    _Float16* x16   = (_Float16*)alloc((size_t)T_ * B_ * WS_ * 2);
    _Float16* hbuf  = (_Float16*)alloc((size_t)4 * B_ * H_ * 2);
    float* hprev32  = (float*)alloc((size_t)B_ * H_ * 4);
    float* h1       = (float*)alloc((size_t)B_ * 64 * 4);
    float* h2       = (float*)alloc((size_t)B_ * LAT_ * 4);
    float* partials = (float*)alloc((size_t)T_ * B_ * 64 * 4);
    unsigned* bar   = (unsigned*)alloc(81920);

    hipMemsetAsync(bar, 0, 81920, stream);

    const int na = 3 * H_ * H_ / 4;
    const int nb = 3 * H_ * WS_ / 4;
    const int nc = T_ * B_ * WS_ / 4;
    const int ntot = na + nb + nc;
    cvt_all<<<(ntot + 255) / 256, 256, 0, stream>>>(
        (const float4*)Whh, (half4*)whh16, na,
        (const float4*)Wih, (half4*)wih16, nb,
        (const float4*)curr, (half4*)x16, nc);

    enc12<<<B_, 64, 0, stream>>>(lag, W1, b1, h1, LAG_);
    enc12<<<B_, LAT_, 0, stream>>>(h1, W2, b2, h2, 64);
    enc3<<<B_, 256, 0, stream>>>(h2, W3, b3, hprev32, hbuf);

    gru_persistent<<<dim3(256), dim3(256), 0, stream>>>(
        hbuf, hprev32, whh16, wih16, x16, bih, bhh, Wo, partials, bar);

    out_reduce<<<T_, B_, 0, stream>>>(partials, bo, out);
}